// Round 1
// baseline (516.130 us; speedup 1.0000x reference)
//
#include <hip/hip_runtime.h>

// RelGraphConv basis-decomposition forward, MI355X.
//
// out[n] = sum_{e: dst_e = n} ( w_comp[et_e,0]*hb[src_e,0,:] + w_comp[et_e,1]*hb[src_e,1,:] )
//          + feat[n] @ loop_weight + h_bias
// where hb[n,b,:] = feat[n] @ weight[b]   (basis-transformed features, staged in d_ws)

constexpr int N_NODES  = 100000;
constexpr int N_EDGES  = 1600000;
constexpr int IN_FEAT  = 64;
constexpr int OUT_FEAT = 64;
constexpr int NUM_BASES = 2;

constexpr int K1_COLS = 192;   // 128 hb columns (2 bases x 64) + 64 loop columns
constexpr int K1_NB   = 8;     // nodes per block-iteration
constexpr int EDGES_PER_BLOCK = 4;  // 4 waves of 64 per block, one edge per wave

// Kernel 1: per-node dense transforms.
//   thread t (< 128)  computes hb[n, t>>6, t&63]
//   thread t (>= 128) computes out[n, t-128] = feat[n]·loop_w[:,t-128] + bias
// Weights (64x192 combined) staged in LDS once per block; feat rows staged
// per 8-node tile. Wl[i][tid] reads are stride-1 across lanes (conflict-free);
// Fl[j][i] is wave-uniform (LDS broadcast).
__global__ __launch_bounds__(K1_COLS) void k1_node_transform(
    const float* __restrict__ feat,        // (N, 64)
    const float* __restrict__ weight,      // (2, 64, 64)
    const float* __restrict__ loop_weight, // (64, 64)
    const float* __restrict__ h_bias,      // (64,)
    float* __restrict__ hb,                // (N, 128)  [ws]
    float* __restrict__ out)               // (N, 64)
{
    __shared__ float Wl[IN_FEAT][K1_COLS];
    __shared__ float Fl[K1_NB][IN_FEAT];
    const int tid = threadIdx.x;

    for (int idx = tid; idx < IN_FEAT * K1_COLS; idx += K1_COLS) {
        const int i = idx / K1_COLS;
        const int c = idx % K1_COLS;
        float v;
        if (c < 128) v = weight[(c >> 6) * (IN_FEAT * OUT_FEAT) + i * OUT_FEAT + (c & 63)];
        else         v = loop_weight[i * OUT_FEAT + (c - 128)];
        Wl[i][c] = v;
    }
    const float bias = (tid >= 128) ? h_bias[tid - 128] : 0.0f;

    for (int base = blockIdx.x * K1_NB; base < N_NODES; base += gridDim.x * K1_NB) {
        __syncthreads();  // also covers initial Wl staging; protects Fl reuse
        for (int idx = tid; idx < K1_NB * IN_FEAT; idx += K1_COLS) {
            const int j = idx >> 6, i = idx & 63;
            const int n = base + j;
            Fl[j][i] = (n < N_NODES) ? feat[n * IN_FEAT + i] : 0.0f;
        }
        __syncthreads();
        #pragma unroll 1
        for (int j = 0; j < K1_NB; ++j) {
            const int n = base + j;
            if (n >= N_NODES) break;
            float acc = 0.0f;
            #pragma unroll
            for (int i = 0; i < IN_FEAT; ++i)
                acc = fmaf(Fl[j][i], Wl[i][tid], acc);
            if (tid < 128) hb[n * 128 + tid] = acc;
            else           out[n * OUT_FEAT + (tid - 128)] = acc + bias;
        }
    }
}

// Kernel 2: one 64-lane wave per edge; lane = output feature.
// Edge scalars hoisted to SGPRs (readfirstlane -> s_load path).
__global__ __launch_bounds__(256) void k2_edges(
    const int*   __restrict__ src,
    const int*   __restrict__ dst,
    const int*   __restrict__ etypes,
    const float* __restrict__ w_comp,   // (64, 2)
    const float* __restrict__ hb,       // (N, 128)
    float* __restrict__ out)            // (N, 64)
{
    const int lane = threadIdx.x & 63;
    const int e = blockIdx.x * EDGES_PER_BLOCK + (threadIdx.x >> 6);
    if (e >= N_EDGES) return;
    const int ei = __builtin_amdgcn_readfirstlane(e);  // wave-uniform by construction

    const int s = src[ei];
    const int d = dst[ei];
    const int r = etypes[ei];
    const float c0 = w_comp[r * 2 + 0];
    const float c1 = w_comp[r * 2 + 1];

    const float* __restrict__ hrow = hb + (size_t)s * 128;
    const float m = c0 * hrow[lane] + c1 * hrow[64 + lane];
    atomicAdd(out + (size_t)d * OUT_FEAT + lane, m);
}

extern "C" void kernel_launch(void* const* d_in, const int* in_sizes, int n_in,
                              void* d_out, int out_size, void* d_ws, size_t ws_size,
                              hipStream_t stream) {
    const float* feat        = (const float*)d_in[0];
    const float* weight      = (const float*)d_in[1];
    const float* w_comp      = (const float*)d_in[2];
    const float* loop_weight = (const float*)d_in[3];
    const float* h_bias      = (const float*)d_in[4];
    const int*   src         = (const int*)d_in[5];
    const int*   dst         = (const int*)d_in[6];
    const int*   etypes      = (const int*)d_in[7];
    float* out = (float*)d_out;
    float* hb  = (float*)d_ws;   // N_NODES * 128 floats = 51.2 MB

    // Kernel 1 fully writes out (self-loop + bias) and hb every call.
    k1_node_transform<<<2048, K1_COLS, 0, stream>>>(feat, weight, loop_weight, h_bias, hb, out);

    const int nblocks = (N_EDGES + EDGES_PER_BLOCK - 1) / EDGES_PER_BLOCK;
    k2_edges<<<nblocks, 256, 0, stream>>>(src, dst, etypes, w_comp, hb, out);
}